// Round 4
// baseline (1637.634 us; speedup 1.0000x reference)
//
#include <hip/hip_runtime.h>

#define NTOK   32768
#define DDIM   512
#define KCODES 8192
#define DK     (DDIM * KCODES)      // 4194304
#define DECAYF 0.8f
#define EPSF   1e-5f

using short8 = __attribute__((ext_vector_type(8))) short;
using f32x4  = __attribute__((ext_vector_type(4))) float;

// ---------------- ws layout (float offsets) ----------------
#define WS_ONEHOT  0                           // [K] float (zeroed)
#define WS_ENORM   KCODES                      // [K] float (zeroed, atomic accum)
#define WS_SCAL    (2 * KCODES)                // [16]: 0=loss, 1=nsum (zeroed)
#define WS_CURSOR  (2 * KCODES + 16)           // [K] int (zeroed)
#define WS_ZERO_BYTES ((size_t)(3 * KCODES + 16) * 4)
#define WS_PART    (3 * KCODES + 16)           // NTOK u64 (memset 0xFF), 8B-aligned
#define WS_IND     (WS_PART + 2 * NTOK)        // [NTOK] int
#define WS_OFF     (WS_IND + NTOK)             // [K] int (code start offsets)
#define WS_SORT    (WS_OFF + KCODES)           // [NTOK] int (token ids by code)
#define WS_ESUMT   (WS_SORT + NTOK)            // [K][D] float (written, not zeroed)
#define WS_EMBEDT  (WS_ESUMT + DK)             // [K][D] fp32 transposed codebook
#define WS_EHI     (WS_EMBEDT + DK)            // [K][D] bf16 hi (DK ushorts)
#define WS_ELO     (WS_EHI + DK / 2)           // [K][D] bf16 lo

__device__ __forceinline__ unsigned short bf16rne(float f) {
  unsigned u = __float_as_uint(f);
  unsigned r = u + 0x7FFFu + ((u >> 16) & 1u);
  return (unsigned short)(r >> 16);
}

__device__ __forceinline__ void gload_lds16(const unsigned short* g, unsigned short* l) {
  __builtin_amdgcn_global_load_lds(
      (const __attribute__((address_space(1))) unsigned int*)g,
      (__attribute__((address_space(3))) unsigned int*)l, 16, 0, 0);
}

// ============ K1: split x into bf16 hi/lo ============
__global__ __launch_bounds__(256) void split_x_kernel(
    const float* __restrict__ x, unsigned short* __restrict__ hi,
    unsigned short* __restrict__ lo) {
  const size_t i = ((size_t)blockIdx.x * 256 + threadIdx.x) * 8;
  const float4 v0 = *(const float4*)&x[i];
  const float4 v1 = *(const float4*)&x[i + 4];
  const float v[8] = {v0.x, v0.y, v0.z, v0.w, v1.x, v1.y, v1.z, v1.w};
  unsigned short h[8], l[8];
#pragma unroll
  for (int j = 0; j < 8; ++j) {
    h[j] = bf16rne(v[j]);
    l[j] = bf16rne(v[j] - __uint_as_float((unsigned)h[j] << 16));
  }
  uint4 H, L;
  H.x = h[0] | ((unsigned)h[1] << 16); H.y = h[2] | ((unsigned)h[3] << 16);
  H.z = h[4] | ((unsigned)h[5] << 16); H.w = h[6] | ((unsigned)h[7] << 16);
  L.x = l[0] | ((unsigned)l[1] << 16); L.y = l[2] | ((unsigned)l[3] << 16);
  L.z = l[4] | ((unsigned)l[5] << 16); L.w = l[6] | ((unsigned)l[7] << 16);
  *(uint4*)&hi[i] = H;
  *(uint4*)&lo[i] = L;
}

// ============ K2: transpose embed [D][K]->[K][D] fp32 + bf16 hi/lo + e_norm ============
__global__ __launch_bounds__(256) void transpose_split_kernel(
    const float* __restrict__ embed, float* __restrict__ embedT,
    unsigned short* __restrict__ ehi, unsigned short* __restrict__ elo,
    float* __restrict__ e_norm) {
  __shared__ float tile[32][33];
  __shared__ float part[8][32];
  const int k0 = blockIdx.x * 32;
  const int d0 = blockIdx.y * 32;
  const int tx = threadIdx.x;   // 0..31
  const int ty = threadIdx.y;   // 0..7
  float sq = 0.f;
#pragma unroll
  for (int j = 0; j < 4; ++j) {
    const int dl = ty + j * 8;
    const float v = embed[(size_t)(d0 + dl) * KCODES + k0 + tx];
    tile[dl][tx] = v;
    sq += v * v;
  }
  part[ty][tx] = sq;
  __syncthreads();
  if (ty == 0) {
    float s = 0.f;
#pragma unroll
    for (int j = 0; j < 8; ++j) s += part[j][tx];
    atomicAdd(&e_norm[k0 + tx], s);
  }
#pragma unroll
  for (int j = 0; j < 4; ++j) {
    const int kl = ty + j * 8;
    const size_t idx = (size_t)(k0 + kl) * DDIM + d0 + tx;
    const float v = tile[tx][kl];
    embedT[idx] = v;
    const unsigned short h = bf16rne(v);
    ehi[idx] = h;
    elo[idx] = bf16rne(v - __uint_as_float((unsigned)h << 16));
  }
}

// ============ K3: fused 3-product bf16-split MFMA dist GEMM + argmin ============
// (unchanged structure from round 3: 128x128 tile, BK=32, XOR swizzle, 0 conflicts)
__global__ __launch_bounds__(256, 3) void argmin_mfma_kernel(
    const unsigned short* __restrict__ xhi, const unsigned short* __restrict__ xlo,
    const unsigned short* __restrict__ ehi, const unsigned short* __restrict__ elo,
    const float* __restrict__ e_norm, unsigned long long* __restrict__ partials) {
  __shared__ unsigned short Ahs[128 * 32];   // 8 KB each
  __shared__ unsigned short Als[128 * 32];
  __shared__ unsigned short Bhs[128 * 32];
  __shared__ unsigned short Bls[128 * 32];

  const int t    = threadIdx.x;
  const int wid  = t >> 6;
  const int lid  = t & 63;
  const int kblk = blockIdx.x;              // 0..63
  const int tokbase = blockIdx.y * 128;
  const int kbase   = kblk * 128;

  const int wrow = wid >> 1, wcol = wid & 1;    // 2x2 wave grid, 64x64 each
  const int m16  = lid & 15, kq = lid >> 4;

  const int srow = lid >> 2;                                  // 0..15
  const int gcol = ((lid & 3) ^ ((srow >> 1) & 3)) * 8;       // swizzled source
  const int fsw  = (kq ^ ((m16 >> 1) & 3)) * 8;               // ds_read swizzle

  f32x4 acc[4][4];
#pragma unroll
  for (int i = 0; i < 4; ++i)
#pragma unroll
    for (int j = 0; j < 4; ++j) acc[i][j] = (f32x4)0.f;

  const unsigned short* Ahg = xhi + (size_t)tokbase * DDIM;
  const unsigned short* Alg = xlo + (size_t)tokbase * DDIM;
  const unsigned short* Bhg = ehi + (size_t)kbase * DDIM;
  const unsigned short* Blg = elo + (size_t)kbase * DDIM;

#pragma unroll 1
  for (int d0 = 0; d0 < DDIM; d0 += 32) {
    __syncthreads();
#pragma unroll
    for (int p = 0; p < 2; ++p) {
      const int chunk = wid + p * 4;                       // wave-uniform
      const size_t go = (size_t)(chunk * 16 + srow) * DDIM + d0 + gcol;
      gload_lds16(Ahg + go, &Ahs[chunk * 512]);
      gload_lds16(Alg + go, &Als[chunk * 512]);
      gload_lds16(Bhg + go, &Bhs[chunk * 512]);
      gload_lds16(Blg + go, &Bls[chunk * 512]);
    }
    __syncthreads();
    short8 bh[4], bl[4];
#pragma unroll
    for (int j = 0; j < 4; ++j) {
      const int r = (wcol * 64 + j * 16 + m16) * 32 + fsw;
      bh[j] = *(const short8*)&Bhs[r];
      bl[j] = *(const short8*)&Bls[r];
    }
#pragma unroll
    for (int i = 0; i < 4; ++i) {
      const int r = (wrow * 64 + i * 16 + m16) * 32 + fsw;
      const short8 ah = *(const short8*)&Ahs[r];
      const short8 al = *(const short8*)&Als[r];
#pragma unroll
      for (int j = 0; j < 4; ++j) {
        acc[i][j] = __builtin_amdgcn_mfma_f32_16x16x32_bf16(ah, bh[j], acc[i][j], 0, 0, 0);
        acc[i][j] = __builtin_amdgcn_mfma_f32_16x16x32_bf16(ah, bl[j], acc[i][j], 0, 0, 0);
        acc[i][j] = __builtin_amdgcn_mfma_f32_16x16x32_bf16(al, bh[j], acc[i][j], 0, 0, 0);
      }
    }
  }

  // ---- fused argmin epilogue: score = e_norm[k] - 2*dot ----
  float en[4];
#pragma unroll
  for (int j = 0; j < 4; ++j)
    en[j] = e_norm[kbase + wcol * 64 + j * 16 + m16];

  __syncthreads();
  unsigned long long* red = (unsigned long long*)Ahs;   // [128][2], 2 KB
#pragma unroll
  for (int i = 0; i < 4; ++i) {
#pragma unroll
    for (int r = 0; r < 4; ++r) {
      unsigned long long best = 0xFFFFFFFFFFFFFFFFull;
#pragma unroll
      for (int j = 0; j < 4; ++j) {
        const float s = en[j] - 2.0f * acc[i][j][r];
        unsigned u = __float_as_uint(s);
        u = (u & 0x80000000u) ? ~u : (u | 0x80000000u);  // orderable bits
        const unsigned k = (unsigned)(kbase + wcol * 64 + j * 16 + m16);
        const unsigned long long c = ((unsigned long long)u << 32) | k;
        best = (c < best) ? c : best;
      }
#pragma unroll
      for (int s = 1; s < 16; s <<= 1) {
        const unsigned long long c = __shfl_xor(best, s);
        best = (c < best) ? c : best;
      }
      if (m16 == 0)
        red[(wrow * 64 + i * 16 + kq * 4 + r) * 2 + wcol] = best;
    }
  }
  __syncthreads();
  if (t < 128) {
    const unsigned long long a0 = red[t * 2], a1 = red[t * 2 + 1];
    const unsigned long long m = (a0 < a1) ? a0 : a1;
    atomicMin(&partials[tokbase + t], m);
  }
}

// ============ K4a: argmin finish -> ind, indf, onehot histogram ============
__global__ __launch_bounds__(256) void argmin_finish_kernel(
    const unsigned long long* __restrict__ partials, int* __restrict__ ind,
    float* __restrict__ indf_out, float* __restrict__ onehot) {
  const int n = blockIdx.x * 256 + threadIdx.x;
  const int k = (int)(partials[n] & 0xFFFFFFFFull);
  ind[n] = k;
  indf_out[n] = (float)k;
  atomicAdd(&onehot[k], 1.0f);
}

// ============ K4b: single-block scan over code counts + cluster EMA + nsum ============
__global__ __launch_bounds__(256) void scan_cluster_kernel(
    const float* __restrict__ onehot, const float* __restrict__ cluster_size,
    int* __restrict__ code_offset, float* __restrict__ ncs_out,
    float* __restrict__ scal) {
  const int t = threadIdx.x;       // 256 threads, 32 codes each
  __shared__ int ssum[256];
  __shared__ float fsum[256];
  int cnt[32];
  int local = 0;
  float ncs_sum = 0.f;
#pragma unroll
  for (int c = 0; c < 32; ++c) {
    const int k = t * 32 + c;
    cnt[c] = (int)onehot[k];
    local += cnt[c];
    const float v = cluster_size[k] * DECAYF + (1.0f - DECAYF) * onehot[k];
    ncs_out[k] = v;
    ncs_sum += v;
  }
  ssum[t] = local;
  fsum[t] = ncs_sum;
  __syncthreads();
  for (int off = 1; off < 256; off <<= 1) {
    const int v = (t >= off) ? ssum[t - off] : 0;
    __syncthreads();
    ssum[t] += v;
    __syncthreads();
  }
  int running = ssum[t] - local;   // exclusive base for this thread's chunk
#pragma unroll
  for (int c = 0; c < 32; ++c) {
    code_offset[t * 32 + c] = running;
    running += cnt[c];
  }
  // reduce ncs_sum -> scal[1]
  for (int off = 128; off > 0; off >>= 1) {
    __syncthreads();
    if (t < off) fsum[t] += fsum[t + off];
  }
  if (t == 0) scal[1] = fsum[0];
}

// ============ K4c: scatter token ids into code-sorted order ============
__global__ __launch_bounds__(256) void scatter_kernel(
    const int* __restrict__ ind, const int* __restrict__ code_offset,
    int* __restrict__ cursor, int* __restrict__ sorted) {
  const int n = blockIdx.x * 256 + threadIdx.x;
  const int k = ind[n];
  const int pos = code_offset[k] + atomicAdd(&cursor[k], 1);
  sorted[pos] = n;
}

// ============ K4d: per-code segment sum (no atomics, coalesced) ============
__global__ __launch_bounds__(128) void segsum_kernel(
    const float* __restrict__ x, const int* __restrict__ sorted,
    const int* __restrict__ code_offset, const float* __restrict__ onehot,
    float* __restrict__ esumT) {
  const int k = blockIdx.x;
  const int off = code_offset[k];
  const int cnt = (int)onehot[k];
  const int d4 = threadIdx.x * 4;
  float4 acc = {0.f, 0.f, 0.f, 0.f};
  for (int tk = 0; tk < cnt; ++tk) {
    const int n = sorted[off + tk];
    const float4 v = *(const float4*)&x[(size_t)n * DDIM + d4];
    acc.x += v.x; acc.y += v.y; acc.z += v.z; acc.w += v.w;
  }
  *(float4*)&esumT[(size_t)k * DDIM + d4] = acc;
}

// ============ K4e: gather quantize + commitment-loss partial ============
__global__ __launch_bounds__(128) void quantize_loss_kernel(
    const float* __restrict__ x, const float* __restrict__ embedT,
    const int* __restrict__ ind, float* __restrict__ quant_out,
    float* __restrict__ scal) {
  const int n = blockIdx.x;
  const int k = ind[n];
  __shared__ float wsum[2];
  const int d4 = threadIdx.x * 4;    // 128 threads * 4 = 512 = DDIM
  const float4 e  = *(const float4*)&embedT[(size_t)k * DDIM + d4];
  const float4 xv = *(const float4*)&x[(size_t)n * DDIM + d4];
  *(float4*)&quant_out[(size_t)n * DDIM + d4] = e;
  const float dx0 = e.x - xv.x, dx1 = e.y - xv.y, dx2 = e.z - xv.z, dx3 = e.w - xv.w;
  float ls = dx0 * dx0 + dx1 * dx1 + dx2 * dx2 + dx3 * dx3;
#pragma unroll
  for (int off = 32; off > 0; off >>= 1) ls += __shfl_down(ls, off);
  if ((threadIdx.x & 63) == 0) wsum[threadIdx.x >> 6] = ls;
  __syncthreads();
  if (threadIdx.x == 0) atomicAdd(&scal[0], wsum[0] + wsum[1]);
}

// ============ K5: finalize via 32x32 transpose tiles (coalesced both sides) ============
__global__ __launch_bounds__(256) void finalize_kernel(
    const float* __restrict__ embed_avg, const float* __restrict__ esumT,
    const float* __restrict__ ncs, const float* __restrict__ scal,
    float* __restrict__ out_embed, float* __restrict__ out_avg,
    float* __restrict__ out_loss) {
  __shared__ float tile[32][33];
  const int k0 = blockIdx.x * 32;
  const int d0 = blockIdx.y * 32;
  const int tx = threadIdx.x;   // 0..31
  const int ty = threadIdx.y;   // 0..7
  // load esumT rows (coalesced along d)
#pragma unroll
  for (int j = 0; j < 4; ++j) {
    const int kl = ty + j * 8;
    tile[kl][tx] = esumT[(size_t)(k0 + kl) * DDIM + d0 + tx];
  }
  const float nsum = scal[1];
  const float cs = (ncs[k0 + tx] + EPSF) / (nsum + (float)KCODES * EPSF) * nsum;
  const float inv_cs = 1.0f / cs;
  __syncthreads();
#pragma unroll
  for (int j = 0; j < 4; ++j) {
    const int dl = ty + j * 8;
    const size_t idx = (size_t)(d0 + dl) * KCODES + k0 + tx;   // [D][K]
    const float ea = embed_avg[idx];
    const float nea = DECAYF * ea + (1.0f - DECAYF) * tile[tx][dl];
    out_avg[idx] = nea;
    out_embed[idx] = nea * inv_cs;
  }
  if (blockIdx.x == 0 && blockIdx.y == 0 && tx == 0 && ty == 0)
    out_loss[0] = scal[0] * (1.0f / ((float)NTOK * (float)DDIM));
}

extern "C" void kernel_launch(void* const* d_in, const int* in_sizes, int n_in,
                              void* d_out, int out_size, void* d_ws, size_t ws_size,
                              hipStream_t stream) {
  (void)in_sizes; (void)n_in; (void)out_size; (void)ws_size;
  const float* x            = (const float*)d_in[0];   // [NTOK, 512]
  const float* embed        = (const float*)d_in[1];   // [D, K]
  const float* cluster_size = (const float*)d_in[2];   // [K]
  const float* embed_avg    = (const float*)d_in[3];   // [D, K]

  float* out = (float*)d_out;
  float* out_quant = out;                               // 16777216
  float* out_indf  = out + 16777216;                    // 32768
  float* out_loss  = out + 16777216 + 32768;            // 1
  float* out_embed = out + 16777216 + 32768 + 1;        // 4194304 (odd offset)
  float* out_ncs   = out_embed + DK;                    // 8192
  float* out_avg   = out_ncs + KCODES;                  // 4194304

  float* ws = (float*)d_ws;
  float* onehot = ws + WS_ONEHOT;
  float* e_norm = ws + WS_ENORM;
  float* scal   = ws + WS_SCAL;
  int*   cursor = (int*)(ws + WS_CURSOR);
  unsigned long long* partials = (unsigned long long*)(ws + WS_PART);
  int*   ind    = (int*)(ws + WS_IND);
  int*   coff   = (int*)(ws + WS_OFF);
  int*   sorted = (int*)(ws + WS_SORT);
  float* esumT  = ws + WS_ESUMT;
  float* embedT = ws + WS_EMBEDT;
  unsigned short* ehi = (unsigned short*)(ws + WS_EHI);
  unsigned short* elo = (unsigned short*)(ws + WS_ELO);

  // x hi/lo scratch lives in the out_quant region; overwritten by quantize later.
  unsigned short* xhi = (unsigned short*)d_out;
  unsigned short* xlo = xhi + (size_t)NTOK * DDIM;

  hipMemsetAsync(d_ws, 0, WS_ZERO_BYTES, stream);
  hipMemsetAsync((char*)d_ws + (size_t)WS_PART * 4, 0xFF, (size_t)NTOK * 8, stream);

  split_x_kernel<<<NTOK * DDIM / 8 / 256, 256, 0, stream>>>(x, xhi, xlo);
  transpose_split_kernel<<<dim3(KCODES / 32, DDIM / 32), dim3(32, 8), 0, stream>>>(
      embed, embedT, ehi, elo, e_norm);

  argmin_mfma_kernel<<<dim3(64, 256), 256, 0, stream>>>(
      xhi, xlo, ehi, elo, e_norm, partials);

  argmin_finish_kernel<<<NTOK / 256, 256, 0, stream>>>(partials, ind, out_indf, onehot);
  scan_cluster_kernel<<<1, 256, 0, stream>>>(onehot, cluster_size, coff, out_ncs, scal);
  scatter_kernel<<<NTOK / 256, 256, 0, stream>>>(ind, coff, cursor, sorted);
  segsum_kernel<<<KCODES, 128, 0, stream>>>(x, sorted, coff, onehot, esumT);
  quantize_loss_kernel<<<NTOK, 128, 0, stream>>>(x, embedT, ind, out_quant, scal);

  finalize_kernel<<<dim3(KCODES / 32, DDIM / 32), dim3(32, 8), 0, stream>>>(
      embed_avg, esumT, out_ncs, scal, out_embed, out_avg, out_loss);
}